// Round 1
// baseline (90.656 us; speedup 1.0000x reference)
//
#include <hip/hip_runtime.h>

#define NCLASS 16
#define D 128
#define EPSF 1e-6f
#define MF 10.0f

// ws layout (floats): S[2048] | Q[16] | CNT[16] | sumLoss,sumValid | bar | done
#define WS_S    0
#define WS_Q    (NCLASS * D)          // 2048
#define WS_CNT  (WS_Q + NCLASS)       // 2064
#define WS_SUM  (WS_CNT + NCLASS)     // 2080 (sumLoss), 2081 (sumValid)
#define WS_BAR  2082                  // phase-1 grid-barrier arrival counter
#define WS_DONE 2083                  // phase-2 completion counter
#define WS_FLOATS 2084

#define BLOCKS 64
#define THREADS 512
#define WAVES (THREADS / 64)          // 8 waves/block, 512 waves total

// Single fused kernel: phase 1 = per-class aggregation (registers ->
// conflict-free LDS -> block tree-reduce -> global atomics, as before),
// then a resident-grid spin barrier (64 blocks on 256 CUs: co-residency
// guaranteed), then phase 2 = per-row loss using the SAME wave->row mapping
// as phase 1 so the F re-read is L1/L2-local to the CU that just read it.
__global__ void __launch_bounds__(THREADS, 1)
fused_kernel(const float* __restrict__ F, const int* __restrict__ L,
             float* __restrict__ ws, float* __restrict__ out, int n) {
    __shared__ float Ssh[WAVES][NCLASS][D];   // 64 KB; reused as S_lds in phase 2
    __shared__ float qsh[WAVES][NCLASS];
    __shared__ float csh[WAVES][NCLASS];
    __shared__ float Stot[D];
    __shared__ float Qcls[NCLASS];
    __shared__ float Ccls[NCLASS];
    __shared__ float Qtot_s;
    __shared__ float redL[WAVES], redV[WAVES];

    const int tid  = threadIdx.x;
    const int lane = tid & 63;
    const int wv   = tid >> 6;
    const int gw   = blockIdx.x * WAVES + wv;
    const int nwv  = BLOCKS * WAVES;          // 512 waves

    // ---------------- phase 1: per-class aggregation ----------------
    float ax[NCLASS], ay[NCLASS], qa[NCLASS], ca[NCLASS];
    #pragma unroll
    for (int c = 0; c < NCLASS; ++c) { ax[c] = ay[c] = qa[c] = ca[c] = 0.f; }

    const float2* __restrict__ F2 = (const float2*)F;
    #pragma unroll 4
    for (int r = gw; r < n; r += nwv) {       // 16 iterations
        const int lc = L[r];                  // wave-uniform broadcast
        const float2 v = F2[(size_t)r * 64 + lane];
        const float sq = fmaf(v.x, v.x, v.y * v.y);
        #pragma unroll
        for (int c = 0; c < NCLASS; ++c) {
            const float sel = (lc == c) ? 1.f : 0.f;
            ax[c] = fmaf(sel, v.x, ax[c]);
            ay[c] = fmaf(sel, v.y, ay[c]);
            qa[c] = fmaf(sel, sq, qa[c]);
            ca[c] += sel;                     // wave-uniform result
        }
    }
    // wave-reduce qa via butterfly (ca needs none: identical in every lane)
    #pragma unroll
    for (int c = 0; c < NCLASS; ++c) {
        float q = qa[c];
        #pragma unroll
        for (int off = 32; off; off >>= 1) q += __shfl_xor(q, off, 64);
        qa[c] = q;
    }
    // conflict-free stores: cell (wv,c,2*lane..2*lane+1) owned by this lane
    #pragma unroll
    for (int c = 0; c < NCLASS; ++c) {
        ((float2*)&Ssh[wv][c][0])[lane] = make_float2(ax[c], ay[c]);
    }
    if (lane == 0) {
        #pragma unroll
        for (int c = 0; c < NCLASS; ++c) { qsh[wv][c] = qa[c]; csh[wv][c] = ca[c]; }
    }
    __syncthreads();
    // block-reduce across waves, then one global atomic per address
    const float* Sflat = &Ssh[0][0][0];
    for (int p = tid; p < NCLASS * D; p += THREADS) {   // 4 iterations
        float s = 0.f;
        #pragma unroll
        for (int w = 0; w < WAVES; ++w) s += Sflat[w * NCLASS * D + p];
        atomicAdd(&ws[WS_S + p], s);
    }
    if (tid < NCLASS) {
        float q = 0.f, cc = 0.f;
        #pragma unroll
        for (int w = 0; w < WAVES; ++w) { q += qsh[w][tid]; cc += csh[w][tid]; }
        atomicAdd(&ws[WS_Q + tid], q);
        atomicAdd(&ws[WS_CNT + tid], cc);
    }

    // ---------------- resident-grid barrier ----------------
    __threadfence();   // drain this thread's atomics to the coherence point
    __syncthreads();   // whole block done publishing before tid0 arrives
    if (tid == 0) {
        __hip_atomic_fetch_add((unsigned*)&ws[WS_BAR], 1u,
                               __ATOMIC_ACQ_REL, __HIP_MEMORY_SCOPE_AGENT);
        while (__hip_atomic_load((unsigned*)&ws[WS_BAR],
                                 __ATOMIC_ACQUIRE, __HIP_MEMORY_SCOPE_AGENT)
               < (unsigned)BLOCKS) { /* spin: 64 waiters only */ }
    }
    __syncthreads();

    // ---------------- phase 2: per-row loss ----------------
    // Reload the globally-summed stats with agent-scope loads (bypass any
    // stale cache line; kernel-boundary coherence no longer applies).
    float* S_lds = &Ssh[0][0][0];             // reuse first 2048 floats of Ssh
    for (int i = tid; i < NCLASS * D; i += THREADS) {
        S_lds[i] = __hip_atomic_load(&ws[WS_S + i], __ATOMIC_RELAXED,
                                     __HIP_MEMORY_SCOPE_AGENT);
    }
    if (tid < NCLASS) {
        Qcls[tid] = __hip_atomic_load(&ws[WS_Q + tid], __ATOMIC_RELAXED,
                                      __HIP_MEMORY_SCOPE_AGENT);
        Ccls[tid] = __hip_atomic_load(&ws[WS_CNT + tid], __ATOMIC_RELAXED,
                                      __HIP_MEMORY_SCOPE_AGENT);
    }
    __syncthreads();
    if (tid < D) {
        float s = 0.f;
        #pragma unroll
        for (int c = 0; c < NCLASS; ++c) s += S_lds[c * D + tid];
        Stot[tid] = s;
    }
    if (tid == 0) {
        float q = 0.f;
        #pragma unroll
        for (int c = 0; c < NCLASS; ++c) q += Qcls[c];
        Qtot_s = q;
    }
    __syncthreads();

    const float nf = (float)n;
    const float2* __restrict__ S2 = (const float2*)S_lds;
    const float2* __restrict__ T2 = (const float2*)Stot;

    float accL = 0.f, accV = 0.f;
    #pragma unroll 2
    for (int r = gw; r < n; r += nwv) {       // 16 iterations, same rows as phase 1
        const int c = L[r];                   // wave-uniform
        const float2 v = F2[(size_t)r * 64 + lane];
        const float2 a = S2[c * 64 + lane];
        const float2 t = T2[lane];
        float sq    = fmaf(v.x, v.x, v.y * v.y);
        float dsame = fmaf(v.x, a.x, v.y * a.y);
        float dtot  = fmaf(v.x, t.x, v.y * t.y);
        #pragma unroll
        for (int off = 32; off; off >>= 1) {
            sq    += __shfl_xor(sq, off, 64);
            dsame += __shfl_xor(dsame, off, 64);
            dtot  += __shfl_xor(dtot, off, 64);
        }
        const float cntc   = Ccls[c];
        const float counts = cntc - 1.f;
        const float same_sum = counts * sq + sq + Qcls[c] - 2.f * dsame;
        const float diff_sum = (nf - cntc) * sq + (Qtot_s - Qcls[c])
                               - 2.f * (dtot - dsame);
        const float loss = same_sum / (counts + EPSF)
                         - diff_sum / (nf - cntc + EPSF) + MF;
        const float valid = counts > 0.5f ? 1.f : 0.f;
        accL += (loss > 0.f ? loss : 0.f) * valid;
        accV += valid;
    }
    if (lane == 0) { redL[wv] = accL; redV[wv] = accV; }
    __syncthreads();
    if (tid == 0) {
        float sL = 0.f, sV = 0.f;
        #pragma unroll
        for (int w = 0; w < WAVES; ++w) { sL += redL[w]; sV += redV[w]; }
        atomicAdd(&ws[WS_SUM], sL);
        atomicAdd(&ws[WS_SUM + 1], sV);
        __threadfence();
        unsigned done = __hip_atomic_fetch_add((unsigned*)&ws[WS_DONE], 1u,
                                               __ATOMIC_ACQ_REL,
                                               __HIP_MEMORY_SCOPE_AGENT);
        if (done == (unsigned)(BLOCKS - 1)) {  // last block: final divide
            float sl = __hip_atomic_load(&ws[WS_SUM], __ATOMIC_RELAXED,
                                         __HIP_MEMORY_SCOPE_AGENT);
            float sv = __hip_atomic_load(&ws[WS_SUM + 1], __ATOMIC_RELAXED,
                                         __HIP_MEMORY_SCOPE_AGENT);
            out[0] = sl / fmaxf(sv, 1.f);
        }
    }
}

extern "C" void kernel_launch(void* const* d_in, const int* in_sizes, int n_in,
                              void* d_out, int out_size, void* d_ws, size_t ws_size,
                              hipStream_t stream) {
    const float* F = (const float*)d_in[0];
    const int* L = (const int*)d_in[1];
    float* out = (float*)d_out;
    float* ws = (float*)d_ws;
    const int n = in_sizes[1];  // 8192 rows; D = in_sizes[0]/n = 128

    hipMemsetAsync(d_ws, 0, WS_FLOATS * sizeof(float), stream);
    fused_kernel<<<BLOCKS, THREADS, 0, stream>>>(F, L, ws, out, n);
}

// Round 2
// 80.802 us; speedup vs baseline: 1.1220x; 1.1220x over previous
//
#include <hip/hip_runtime.h>

#define NCLASS 16
#define D 128
#define EPSF 1e-6f
#define MF 10.0f

// ws layout (floats): S[2048] | Q[16] | CNT[16] | sumLoss,sumValid | done
#define WS_S   0
#define WS_Q   (NCLASS * D)       // 2048
#define WS_CNT (WS_Q + NCLASS)    // 2064
#define WS_SUM (WS_CNT + NCLASS)  // 2080 (sumLoss), 2081 (sumValid)
#define WS_DONE 2082              // uint completion counter
#define WS_FLOATS 2084

#define AGG_BLOCKS 64
#define AGG_THREADS 512
#define AGG_WAVES (AGG_THREADS / 64)

// Per-class aggregation. NO LDS atomics (round-2 lesson: same-address DS RMW
// serializes 64-way). Registers -> conflict-free LDS stores -> block
// tree-reduce -> one global atomicAdd per (block, address).
// Round-1 lesson: do NOT fuse with loss via a resident-grid spin barrier —
// cross-XCD spin + occupancy collapse cost ~6 us vs the ~1 us kernel-boundary.
__global__ void __launch_bounds__(AGG_THREADS)
agg_kernel(const float* __restrict__ F, const int* __restrict__ L,
           float* __restrict__ ws, int n) {
    __shared__ float Ssh[AGG_WAVES][NCLASS][D];   // 64 KB
    __shared__ float qsh[AGG_WAVES][NCLASS];
    __shared__ float csh[AGG_WAVES][NCLASS];
    const int tid  = threadIdx.x;
    const int lane = tid & 63;
    const int wv   = tid >> 6;
    const int gw   = blockIdx.x * AGG_WAVES + wv;
    const int nwv  = AGG_BLOCKS * AGG_WAVES;      // 512 waves

    float ax[NCLASS], ay[NCLASS], qa[NCLASS], ca[NCLASS];
    #pragma unroll
    for (int c = 0; c < NCLASS; ++c) { ax[c] = ay[c] = qa[c] = ca[c] = 0.f; }

    const float2* __restrict__ F2 = (const float2*)F;
    #pragma unroll 8
    for (int r = gw; r < n; r += nwv) {           // 16 iterations, 8 loads in flight
        const int lc = L[r];                      // wave-uniform broadcast
        const float2 v = F2[(size_t)r * 64 + lane];
        const float sq = fmaf(v.x, v.x, v.y * v.y);
        #pragma unroll
        for (int c = 0; c < NCLASS; ++c) {
            const float sel = (lc == c) ? 1.f : 0.f;
            ax[c] = fmaf(sel, v.x, ax[c]);
            ay[c] = fmaf(sel, v.y, ay[c]);
            qa[c] = fmaf(sel, sq, qa[c]);
            ca[c] += sel;                         // wave-uniform result
        }
    }
    // wave-reduce qa via butterfly (ca needs none: identical in every lane)
    #pragma unroll
    for (int c = 0; c < NCLASS; ++c) {
        float q = qa[c];
        #pragma unroll
        for (int off = 32; off; off >>= 1) q += __shfl_xor(q, off, 64);
        qa[c] = q;
    }
    // conflict-free stores: cell (wv,c,2*lane..2*lane+1) owned by this lane
    #pragma unroll
    for (int c = 0; c < NCLASS; ++c) {
        ((float2*)&Ssh[wv][c][0])[lane] = make_float2(ax[c], ay[c]);
    }
    if (lane == 0) {
        #pragma unroll
        for (int c = 0; c < NCLASS; ++c) { qsh[wv][c] = qa[c]; csh[wv][c] = ca[c]; }
    }
    __syncthreads();
    // block-reduce across waves, then one global atomic per address
    const float* Sflat = &Ssh[0][0][0];
    for (int p = tid; p < NCLASS * D; p += AGG_THREADS) {  // 4 iterations
        float s = 0.f;
        #pragma unroll
        for (int w = 0; w < AGG_WAVES; ++w) s += Sflat[w * NCLASS * D + p];
        atomicAdd(&ws[WS_S + p], s);
    }
    if (tid < NCLASS) {
        float q = 0.f, cc = 0.f;
        #pragma unroll
        for (int w = 0; w < AGG_WAVES; ++w) { q += qsh[w][tid]; cc += csh[w][tid]; }
        atomicAdd(&ws[WS_Q + tid], q);
        atomicAdd(&ws[WS_CNT + tid], cc);
    }
}

#define LOSS_BLOCKS 256
#define LOSS_THREADS 256
#define LOSS_WAVES (LOSS_THREADS / 64)

// One wave per row (8 rows/wave). Block-reduces loss/valid -> 2 global atomics
// per block. Final division fused via done-counter (last block writes out).
__global__ void __launch_bounds__(LOSS_THREADS)
loss_kernel(const float* __restrict__ F, const int* __restrict__ L,
            float* __restrict__ ws, float* __restrict__ out, int n) {
    __shared__ float S_lds[NCLASS * D];
    __shared__ float Stot[D];
    __shared__ float Q_lds[NCLASS];
    __shared__ float cnt_lds[NCLASS];
    __shared__ float Qtot_s;
    __shared__ float redL[LOSS_WAVES], redV[LOSS_WAVES];

    const int tid = threadIdx.x;
    const float4* ws4 = (const float4*)(ws + WS_S);
    float4* S4 = (float4*)S_lds;
    for (int i = tid; i < NCLASS * D / 4; i += LOSS_THREADS) S4[i] = ws4[i];
    if (tid < NCLASS) {
        Q_lds[tid] = ws[WS_Q + tid];
        cnt_lds[tid] = ws[WS_CNT + tid];
    }
    __syncthreads();
    if (tid < D) {
        float s = 0.f;
        #pragma unroll
        for (int c = 0; c < NCLASS; ++c) s += S_lds[c * D + tid];
        Stot[tid] = s;
    }
    if (tid == 0) {
        float q = 0.f;
        #pragma unroll
        for (int c = 0; c < NCLASS; ++c) q += Q_lds[c];
        Qtot_s = q;
    }
    __syncthreads();

    const int lane = tid & 63;
    const int wv = tid >> 6;
    const int gw = blockIdx.x * LOSS_WAVES + wv;
    const int nw = LOSS_BLOCKS * LOSS_WAVES;   // 1024 waves
    const float nf = (float)n;
    const float2* __restrict__ F2 = (const float2*)F;
    const float2* __restrict__ S2 = (const float2*)S_lds;
    const float2* __restrict__ T2 = (const float2*)Stot;

    float accL = 0.f, accV = 0.f;
    #pragma unroll 4
    for (int r = gw; r < n; r += nw) {          // 8 iterations, 4 loads in flight
        const int c = L[r];                      // wave-uniform
        const float2 v = F2[(size_t)r * 64 + lane];
        const float2 a = S2[c * 64 + lane];
        const float2 t = T2[lane];
        float sq    = fmaf(v.x, v.x, v.y * v.y);
        float dsame = fmaf(v.x, a.x, v.y * a.y);
        float dtot  = fmaf(v.x, t.x, v.y * t.y);
        #pragma unroll
        for (int off = 32; off; off >>= 1) {
            sq    += __shfl_xor(sq, off, 64);
            dsame += __shfl_xor(dsame, off, 64);
            dtot  += __shfl_xor(dtot, off, 64);
        }
        const float cntc   = cnt_lds[c];
        const float counts = cntc - 1.f;
        const float same_sum = counts * sq + sq + Q_lds[c] - 2.f * dsame;
        const float diff_sum = (nf - cntc) * sq + (Qtot_s - Q_lds[c])
                               - 2.f * (dtot - dsame);
        const float loss = same_sum / (counts + EPSF)
                         - diff_sum / (nf - cntc + EPSF) + MF;
        const float valid = counts > 0.5f ? 1.f : 0.f;
        accL += (loss > 0.f ? loss : 0.f) * valid;
        accV += valid;
    }
    if (lane == 0) { redL[wv] = accL; redV[wv] = accV; }
    __syncthreads();
    if (tid == 0) {
        float sL = 0.f, sV = 0.f;
        #pragma unroll
        for (int w = 0; w < LOSS_WAVES; ++w) { sL += redL[w]; sV += redV[w]; }
        atomicAdd(&ws[WS_SUM], sL);
        atomicAdd(&ws[WS_SUM + 1], sV);
        __threadfence();
        unsigned done = __hip_atomic_fetch_add((unsigned*)&ws[WS_DONE], 1u,
                                               __ATOMIC_ACQ_REL,
                                               __HIP_MEMORY_SCOPE_AGENT);
        if (done == (unsigned)(gridDim.x - 1)) {   // last block: final divide
            float sl = __hip_atomic_load(&ws[WS_SUM], __ATOMIC_RELAXED,
                                         __HIP_MEMORY_SCOPE_AGENT);
            float sv = __hip_atomic_load(&ws[WS_SUM + 1], __ATOMIC_RELAXED,
                                         __HIP_MEMORY_SCOPE_AGENT);
            out[0] = sl / fmaxf(sv, 1.f);
        }
    }
}

extern "C" void kernel_launch(void* const* d_in, const int* in_sizes, int n_in,
                              void* d_out, int out_size, void* d_ws, size_t ws_size,
                              hipStream_t stream) {
    const float* F = (const float*)d_in[0];
    const int* L = (const int*)d_in[1];
    float* out = (float*)d_out;
    float* ws = (float*)d_ws;
    const int n = in_sizes[1];  // 8192 rows; D = in_sizes[0]/n = 128

    hipMemsetAsync(d_ws, 0, WS_FLOATS * sizeof(float), stream);
    agg_kernel<<<AGG_BLOCKS, AGG_THREADS, 0, stream>>>(F, L, ws, n);
    loss_kernel<<<LOSS_BLOCKS, LOSS_THREADS, 0, stream>>>(F, L, ws, out, n);
}